// Round 5
// baseline (219.768 us; speedup 1.0000x reference)
//
#include <hip/hip_runtime.h>

#define NDRUG 591
#define FDIM 1024
#define NEDGE 120000
#define MPAD 640
#define ASTRIDE 349281          // 591*591 (fp32 temp adjacency, unnormalized)
#define ABSTRIDE (MPAD*MPAD)    // 409600  (bf16 padded adjacency)
#define HSTRIDE (MPAD*FDIM)     // 655360  (bf16 padded node features)
#define REAL (NDRUG*FDIM)       // 605184  real (row-contiguous) elements
#define WSTRIDE (FDIM*FDIM)     // 1048576

typedef __attribute__((ext_vector_type(8))) short bf16x8;
typedef __attribute__((ext_vector_type(4))) float f32x4;
typedef __attribute__((ext_vector_type(4))) unsigned short u16x4;

static __device__ __forceinline__ unsigned short f2bf(float f) {
    unsigned u = __builtin_bit_cast(unsigned, f);
    u += 0x7fffu + ((u >> 16) & 1u);            // RNE
    return (unsigned short)(u >> 16);
}
static __device__ __forceinline__ float bf2f(unsigned short h) {
    return __builtin_bit_cast(float, ((unsigned)h) << 16);
}

typedef const __attribute__((address_space(1))) unsigned int* gp1_t;
typedef __attribute__((address_space(3))) unsigned int* lp3_t;
static __device__ __forceinline__ void gload16(const void* g, unsigned short* l) {
    __builtin_amdgcn_global_load_lds((gp1_t)g, (lp3_t)l, 16, 0, 0);
}

// ---------------- init: zero fp32 A (vectorized), zero pool acc ----------------
__global__ void init_kernel(float* AmatF, float* scal) {
    int i = blockIdx.x * blockDim.x + threadIdx.x;
    const int TOT = 3 * ASTRIDE;
    int b = i * 4;
    if (b + 3 < TOT) {
        *(float4*)(AmatF + b) = make_float4(0.f, 0.f, 0.f, 0.f);
    } else if (b < TOT) {
        for (int j = b; j < TOT; ++j) AmatF[j] = 0.f;
    }
    if (i < 16) scal[i] = 0.f;
}

// ---------------- raw edge-weight scatter + self-loop (+1 on diagonal) ----------------
__global__ void scatter_kernel(const int* e_t, const float* w_t,
                               const int* e_s, const float* w_s,
                               const int* e_g, const float* w_g, float* AmatF) {
    int i = blockIdx.x * blockDim.x + threadIdx.x;
    const int PER = NEDGE + NDRUG;
    if (i >= 3 * PER) return;
    int g = i / PER, r = i - g * PER;
    float* Ag = AmatF + (long)g * ASTRIDE;
    if (r < NEDGE) {
        const int*   E_ = (g == 0) ? e_t : (g == 1) ? e_s : e_g;
        const float* W_ = (g == 0) ? w_t : (g == 1) ? w_s : w_g;
        int src = E_[r], dst = E_[NEDGE + r];
        atomicAdd(Ag + (long)dst * NDRUG + src, W_[r]);
    } else {
        int n = r - NEDGE;
        atomicAdd(Ag + (long)n * NDRUG + n, 1.0f);      // self-loop weight 1
    }
}

// ---------------- deg = rowsum(A); dinv = rsqrt(deg) ----------------
__global__ void rowdeg_kernel(const float* AmatF, float* dinv) {
    int r = blockIdx.x, g = blockIdx.y;
    const float* row = AmatF + (long)g * ASTRIDE + (long)r * NDRUG;
    float s = 0.f;
    for (int c = threadIdx.x; c < NDRUG; c += 64) s += row[c];
#pragma unroll
    for (int off = 32; off > 0; off >>= 1) s += __shfl_down(s, off);
    if (threadIdx.x == 0)
        dinv[g * NDRUG + r] = (s > 0.f) ? rsqrtf(s) : 0.f;
}

// ---------------- fused normalize + bf16 convert + pad ----------------
__global__ void conv_A(const float* AmatF, const float* dinv, unsigned short* Amatb) {
    int r = blockIdx.x, g = blockIdx.y;
    int t = threadIdx.x;
    if (t >= 160) return;
    int c = t * 4;
    u16x4 o = {0, 0, 0, 0};
    if (r < NDRUG) {
        const float* src = AmatF + (long)g * ASTRIDE + (long)r * NDRUG;
        const float* dv = dinv + g * NDRUG;
        float dr = dv[r];
#pragma unroll
        for (int j = 0; j < 4; j++) {
            int cc = c + j;
            if (cc < NDRUG) o[j] = f2bf(src[cc] * dv[cc] * dr);
        }
    }
    *(u16x4*)(Amatb + (long)g * ABSTRIDE + (long)r * MPAD + c) = o;
}

// dm1 [591][1024] fp32 -> dm1b [640][1024] bf16, zero-padded
__global__ void conv_dm1(const float* dm1, unsigned short* dm1b) {
    int r = blockIdx.x;
    int c = threadIdx.x * 4;
    u16x4 o = {0, 0, 0, 0};
    if (r < NDRUG) {
        float4 v = *(const float4*)(dm1 + (long)r * FDIM + c);
        o[0] = f2bf(v.x); o[1] = f2bf(v.y); o[2] = f2bf(v.z); o[3] = f2bf(v.w);
    }
    *(u16x4*)(dm1b + (long)r * FDIM + c) = o;
}

// W [K][N] fp32 -> WT [N][K] bf16, all 6 matrices (order t1,s1,g1,t2,s2,g2)
__global__ void conv_w6(const float* w0, const float* w1, const float* w2,
                        const float* w3, const float* w4, const float* w5,
                        unsigned short* WTb) {
    __shared__ float s[32][33];
    int z = blockIdx.z;
    const float* W = (z == 0) ? w0 : (z == 1) ? w1 : (z == 2) ? w2
                   : (z == 3) ? w3 : (z == 4) ? w4 : w5;
    unsigned short* WT = WTb + (long)z * WSTRIDE;
    int n0 = blockIdx.x * 32, k0 = blockIdx.y * 32;
    int tx = threadIdx.x & 31, ty = threadIdx.x >> 5;   // ty 0..7
#pragma unroll
    for (int p = 0; p < 4; p++)
        s[ty + 8 * p][tx] = W[(long)(k0 + ty + 8 * p) * FDIM + n0 + tx];
    __syncthreads();
#pragma unroll
    for (int p = 0; p < 4; p++)
        WT[(long)(n0 + ty + 8 * p) * FDIM + k0 + tx] = f2bf(s[tx][ty + 8 * p]);
}

// ---------------- bf16 MFMA GEMM (counted-vmcnt pipelined 2-phase) ----------------
// C[m][n] = sum_k A[m][k] * BT[n][k]   (A: [Mpad][ldaK], BT: [N][ldbK], both bf16)
// EPI=0: store C transposed bf16 (C[n][m], ldC=MPAD); EPI=1: +bias, relu, normal layout
template <int EPI>
__global__ __launch_bounds__(256) void mfma_gemm(
    const unsigned short* __restrict__ Abase, long strideA, int ldaK,
    const unsigned short* __restrict__ Bbase, long strideB, int ldbK,
    const float* __restrict__ bias0, const float* __restrict__ bias1,
    const float* __restrict__ bias2,
    unsigned short* __restrict__ Cbase, long strideC, int ldC, int K)
{
    __shared__ unsigned short ldsA[2][4096];
    __shared__ unsigned short ldsB[2][4096];

    const int g = blockIdx.z;
    const unsigned short* A = Abase + (long)g * strideA;
    const unsigned short* B = Bbase + (long)g * strideB;
    unsigned short* C = Cbase + (long)g * strideC;
    const float* bias = (g == 0) ? bias0 : (g == 1) ? bias1 : bias2;

    const int m0 = blockIdx.y * 64;
    const int n0 = blockIdx.x * 64;
    const int tid = threadIdx.x;
    const int w = tid >> 6, lane = tid & 63;
    const int l15 = lane & 15, lq = lane >> 4;
    const int wm = w >> 1, wn = w & 1;

    // staging geometry: seg = 2w or 2w+1 covers tile rows [8*seg, 8*seg+8)
    const int sr  = lane >> 3;                  // row within segment
    const int kcs = 8 * ((lane & 7) ^ sr);      // pre-swizzled k element offset
    const int segA0 = 2 * w, segA1 = 2 * w + 1;
    const int rA0 = segA0 * 8 + sr, rA1 = segA1 * 8 + sr;

    // fragment ds_read offsets (elements), swizzled to match staging
    int offA[2][2], offB[2][2];
    {
        int ra0 = 32 * wm + l15, ra1 = ra0 + 16;
        int rb0 = 32 * wn + l15, rb1 = rb0 + 16;
        offA[0][0] = ra0 * 64 + ((lq    ) ^ (ra0 & 7)) * 8;
        offA[0][1] = ra0 * 64 + ((lq + 4) ^ (ra0 & 7)) * 8;
        offA[1][0] = ra1 * 64 + ((lq    ) ^ (ra1 & 7)) * 8;
        offA[1][1] = ra1 * 64 + ((lq + 4) ^ (ra1 & 7)) * 8;
        offB[0][0] = rb0 * 64 + ((lq    ) ^ (rb0 & 7)) * 8;
        offB[0][1] = rb0 * 64 + ((lq + 4) ^ (rb0 & 7)) * 8;
        offB[1][0] = rb1 * 64 + ((lq    ) ^ (rb1 & 7)) * 8;
        offB[1][1] = rb1 * 64 + ((lq + 4) ^ (rb1 & 7)) * 8;
    }

    f32x4 acc00 = {0.f, 0.f, 0.f, 0.f}, acc01 = {0.f, 0.f, 0.f, 0.f};
    f32x4 acc10 = {0.f, 0.f, 0.f, 0.f}, acc11 = {0.f, 0.f, 0.f, 0.f};

    const int nt = K >> 6;

#define STAGE(bf, k0c) do {                                                        \
    gload16(A + (long)(m0 + rA0) * ldaK + (k0c) + kcs, &ldsA[bf][segA0 * 512]);    \
    gload16(A + (long)(m0 + rA1) * ldaK + (k0c) + kcs, &ldsA[bf][segA1 * 512]);    \
    gload16(B + (long)(n0 + rA0) * ldbK + (k0c) + kcs, &ldsB[bf][segA0 * 512]);    \
    gload16(B + (long)(n0 + rA1) * ldbK + (k0c) + kcs, &ldsB[bf][segA1 * 512]);    \
} while (0)

    STAGE(0, 0);    // 4 loads in flight

    for (int t = 0; t < nt; ++t) {
        const int cur = t & 1;
        if (t + 1 < nt) {
            STAGE(cur ^ 1, (t + 1) << 6);               // 8 in flight
            asm volatile("s_waitcnt vmcnt(4)");         // tile t landed; t+1 stays in flight
        } else {
            asm volatile("s_waitcnt vmcnt(0)");         // last tile: drain
        }
        __builtin_amdgcn_s_barrier();                   // all waves: buf[cur] ready
        __builtin_amdgcn_sched_barrier(0);
        const unsigned short* pa = ldsA[cur];
        const unsigned short* pb = ldsB[cur];
        {
            bf16x8 a0 = *(const bf16x8*)(pa + offA[0][0]);
            bf16x8 a1 = *(const bf16x8*)(pa + offA[1][0]);
            bf16x8 b0 = *(const bf16x8*)(pb + offB[0][0]);
            bf16x8 b1 = *(const bf16x8*)(pb + offB[1][0]);
            acc00 = __builtin_amdgcn_mfma_f32_16x16x32_bf16(a0, b0, acc00, 0, 0, 0);
            acc01 = __builtin_amdgcn_mfma_f32_16x16x32_bf16(a0, b1, acc01, 0, 0, 0);
            acc10 = __builtin_amdgcn_mfma_f32_16x16x32_bf16(a1, b0, acc10, 0, 0, 0);
            acc11 = __builtin_amdgcn_mfma_f32_16x16x32_bf16(a1, b1, acc11, 0, 0, 0);
        }
        {
            bf16x8 a0 = *(const bf16x8*)(pa + offA[0][1]);
            bf16x8 a1 = *(const bf16x8*)(pa + offA[1][1]);
            bf16x8 b0 = *(const bf16x8*)(pb + offB[0][1]);
            bf16x8 b1 = *(const bf16x8*)(pb + offB[1][1]);
            acc00 = __builtin_amdgcn_mfma_f32_16x16x32_bf16(a0, b0, acc00, 0, 0, 0);
            acc01 = __builtin_amdgcn_mfma_f32_16x16x32_bf16(a0, b1, acc01, 0, 0, 0);
            acc10 = __builtin_amdgcn_mfma_f32_16x16x32_bf16(a1, b0, acc10, 0, 0, 0);
            acc11 = __builtin_amdgcn_mfma_f32_16x16x32_bf16(a1, b1, acc11, 0, 0, 0);
        }
        asm volatile("s_waitcnt lgkmcnt(0)");           // reads of buf[cur] complete
        __builtin_amdgcn_sched_barrier(0);
        __builtin_amdgcn_s_barrier();                   // release buf[cur] for overwrite
    }
#undef STAGE

    // epilogue: D layout col=lane&15, row=(lane>>4)*4+reg   [m89-verified]
    if (EPI == 0) {
#define TSTORE(accv, mo, no) do {                                   \
        int nn = n0 + 32 * wn + (no) * 16 + l15;                    \
        int mm = m0 + 32 * wm + (mo) * 16 + lq * 4;                 \
        u16x4 pk;                                                   \
        pk[0] = f2bf(accv[0]); pk[1] = f2bf(accv[1]);               \
        pk[2] = f2bf(accv[2]); pk[3] = f2bf(accv[3]);               \
        *(u16x4*)&C[(long)nn * ldC + mm] = pk;                      \
} while (0)
        TSTORE(acc00, 0, 0); TSTORE(acc01, 0, 1);
        TSTORE(acc10, 1, 0); TSTORE(acc11, 1, 1);
#undef TSTORE
    } else {
#define NSTORE(accv, mo, no) do {                                   \
        int nn = n0 + 32 * wn + (no) * 16 + l15;                    \
        int mm = m0 + 32 * wm + (mo) * 16 + lq * 4;                 \
        float bs = bias[nn];                                        \
        C[(long)(mm + 0) * ldC + nn] = f2bf(fmaxf(accv[0] + bs, 0.f)); \
        C[(long)(mm + 1) * ldC + nn] = f2bf(fmaxf(accv[1] + bs, 0.f)); \
        C[(long)(mm + 2) * ldC + nn] = f2bf(fmaxf(accv[2] + bs, 0.f)); \
        C[(long)(mm + 3) * ldC + nn] = f2bf(fmaxf(accv[3] + bs, 0.f)); \
} while (0)
        NSTORE(acc00, 0, 0); NSTORE(acc01, 0, 1);
        NSTORE(acc10, 1, 0); NSTORE(acc11, 1, 1);
#undef NSTORE
    }
}

// ---------------- pooling over bf16 channels ----------------
__global__ void pool_kernel(const unsigned short* h1b, const unsigned short* h2b,
                            float* acc) {
    int ch = blockIdx.y;
    const unsigned short* p = ((ch & 1) ? h2b : h1b) + (long)(ch >> 1) * HSTRIDE;
    const int nv = REAL / 8;
    float s = 0.f;
    for (int i = blockIdx.x * blockDim.x + threadIdx.x; i < nv;
         i += gridDim.x * blockDim.x) {
        bf16x8 v = *(const bf16x8*)(p + (long)i * 8);
#pragma unroll
        for (int j = 0; j < 8; j++) s += bf2f((unsigned short)v[j]);
    }
#pragma unroll
    for (int off = 32; off > 0; off >>= 1) s += __shfl_down(s, off);
    if ((threadIdx.x & 63) == 0) atomicAdd(acc + ch, s);
}

__global__ void mlp_kernel(const float* acc, const float* fc1w, const float* fc1b,
                           const float* fc2w, const float* fc2b, const float* convw,
                           float* wout) {
    if (threadIdx.x != 0 || blockIdx.x != 0) return;
    float pool[6];
    const float inv = 1.0f / (float)REAL;
    for (int c = 0; c < 6; c++) pool[c] = acc[c] * inv;
    float h[30];
    for (int k = 0; k < 30; k++) {
        float s = fc1b[k];
        for (int c = 0; c < 6; c++) s += pool[c] * fc1w[k * 6 + c];
        h[k] = fmaxf(s, 0.f);
    }
    for (int j = 0; j < 6; j++) {
        float s = fc2b[j];
        for (int k = 0; k < 30; k++) s += h[k] * fc2w[j * 30 + k];
        float a = 1.0f / (1.0f + expf(-s));
        wout[j] = convw[j] * a;
    }
}

__global__ void combine_kernel(const unsigned short* h1b, const unsigned short* h2b,
                               const float* wv, const float* convb, float* out) {
    int i = blockIdx.x * 256 + threadIdx.x;
    const int nv = REAL / 8;
    if (i >= nv) return;
    float cb = convb[0];
    float r[8];
#pragma unroll
    for (int j = 0; j < 8; j++) r[j] = cb;
#define ACCCH(c, ptr) do {                                          \
        float wc = wv[c];                                           \
        bf16x8 v = *(const bf16x8*)((ptr) + (long)i * 8);           \
        _Pragma("unroll")                                           \
        for (int j = 0; j < 8; j++) r[j] += wc * bf2f((unsigned short)v[j]); \
} while (0)
    ACCCH(0, h1b);
    ACCCH(1, h2b);
    ACCCH(2, h1b + HSTRIDE);
    ACCCH(3, h2b + HSTRIDE);
    ACCCH(4, h1b + 2 * HSTRIDE);
    ACCCH(5, h2b + 2 * HSTRIDE);
#undef ACCCH
    float4 o0 = make_float4(r[0], r[1], r[2], r[3]);
    float4 o1 = make_float4(r[4], r[5], r[6], r[7]);
    *(float4*)(out + (long)i * 8) = o0;
    *(float4*)(out + (long)i * 8 + 4) = o1;
}

extern "C" void kernel_launch(void* const* d_in, const int* in_sizes, int n_in,
                              void* d_out, int out_size, void* d_ws, size_t ws_size,
                              hipStream_t stream) {
    const float* dm1 = (const float*)d_in[0];
    const int*   e_t = (const int*)d_in[1];
    const float* w_t = (const float*)d_in[2];
    const int*   e_s = (const int*)d_in[3];
    const float* w_s = (const float*)d_in[4];
    const int*   e_g = (const int*)d_in[5];
    const float* w_g = (const float*)d_in[6];
    const float* W_t1 = (const float*)d_in[7];
    const float* b_t1 = (const float*)d_in[8];
    const float* W_t2 = (const float*)d_in[9];
    const float* b_t2 = (const float*)d_in[10];
    const float* W_s1 = (const float*)d_in[11];
    const float* b_s1 = (const float*)d_in[12];
    const float* W_s2 = (const float*)d_in[13];
    const float* b_s2 = (const float*)d_in[14];
    const float* W_g1 = (const float*)d_in[15];
    const float* b_g1 = (const float*)d_in[16];
    const float* W_g2 = (const float*)d_in[17];
    const float* b_g2 = (const float*)d_in[18];
    const float* fc1w = (const float*)d_in[19];
    const float* fc1b = (const float*)d_in[20];
    const float* fc2w = (const float*)d_in[21];
    const float* fc2b = (const float*)d_in[22];
    const float* convw = (const float*)d_in[23];
    const float* convb = (const float*)d_in[24];
    float* out = (float*)d_out;

    // workspace layout (bytes):
    //   WTb   : 6 weight mats bf16, 12,582,912 B
    //   AmatF : fp32 adjacency 4,191,372 B — ALIASES WTb[0..] (dead before conv_w6)
    //   h2b   : ALIASES WTb layer-2 half (dead after stage-2 GEMM)
    char* base = (char*)d_ws;
    unsigned short* WTb = (unsigned short*)base;
    float* AmatF = (float*)base;
    unsigned short* h2b = (unsigned short*)(base + (size_t)3 * WSTRIDE * 2);
    size_t o = (size_t)6 * WSTRIDE * 2;
    float* dinv = (float*)(base + o); o += 8192;
    float* scal = (float*)(base + o); o += 256;
    unsigned short* dm1b  = (unsigned short*)(base + o); o += (size_t)MPAD * FDIM * 2;
    unsigned short* Amatb = (unsigned short*)(base + o); o += (size_t)3 * ABSTRIDE * 2;
    unsigned short* xwT   = (unsigned short*)(base + o); o += (size_t)3 * HSTRIDE * 2;
    unsigned short* h1b   = (unsigned short*)(base + o); o += (size_t)3 * HSTRIDE * 2;
    if (ws_size < o) return;   // refuse to fault if workspace too small (24.2 MB)

    // dense adjacency: zero -> raw scatter (+1 diag) -> rowsum deg -> normalize+bf16
    init_kernel<<<(3 * ASTRIDE / 4 + 256) / 256, 256, 0, stream>>>(AmatF, scal);
    scatter_kernel<<<(3 * (NEDGE + NDRUG) + 255) / 256, 256, 0, stream>>>(
        e_t, w_t, e_s, w_s, e_g, w_g, AmatF);
    rowdeg_kernel<<<dim3(NDRUG, 3), 64, 0, stream>>>(AmatF, dinv);
    conv_A<<<dim3(MPAD, 3), 256, 0, stream>>>(AmatF, dinv, Amatb);
    conv_w6<<<dim3(32, 32, 6), 256, 0, stream>>>(
        W_t1, W_s1, W_g1, W_t2, W_s2, W_g2, WTb);    // overwrites AmatF alias (dead)
    conv_dm1<<<MPAD, 256, 0, stream>>>(dm1, dm1b);

    dim3 gg(FDIM / 64, MPAD / 64, 3);
    // stage 1: xwT = (dm1b @ W1)^T
    mfma_gemm<0><<<gg, 256, 0, stream>>>(
        dm1b, 0L, FDIM, WTb, (long)WSTRIDE, FDIM,
        nullptr, nullptr, nullptr, xwT, (long)HSTRIDE, MPAD, FDIM);
    // agg 1: h1 = relu(A @ xw + b1)
    mfma_gemm<1><<<gg, 256, 0, stream>>>(
        Amatb, (long)ABSTRIDE, MPAD, xwT, (long)HSTRIDE, MPAD,
        b_t1, b_s1, b_g1, h1b, (long)HSTRIDE, FDIM, MPAD);
    // stage 2: xwT = (h1 @ W2)^T   (consumes WTb layer-2 half)
    mfma_gemm<0><<<gg, 256, 0, stream>>>(
        h1b, (long)HSTRIDE, FDIM, WTb + (size_t)3 * WSTRIDE, (long)WSTRIDE, FDIM,
        nullptr, nullptr, nullptr, xwT, (long)HSTRIDE, MPAD, FDIM);
    // agg 2: h2 = relu(A @ xw + b2)   (h2b aliases the now-dead WTb layer-2 half)
    mfma_gemm<1><<<gg, 256, 0, stream>>>(
        Amatb, (long)ABSTRIDE, MPAD, xwT, (long)HSTRIDE, MPAD,
        b_t2, b_s2, b_g2, h2b, (long)HSTRIDE, FDIM, MPAD);

    pool_kernel<<<dim3(32, 6), 256, 0, stream>>>(h1b, h2b, scal);
    mlp_kernel<<<1, 64, 0, stream>>>(scal, fc1w, fc1b, fc2w, fc2b, convw, scal + 8);
    combine_kernel<<<(REAL / 8 + 255) / 256, 256, 0, stream>>>(h1b, h2b, scal + 8, convb, out);
}

// Round 8
// 218.962 us; speedup vs baseline: 1.0037x; 1.0037x over previous
//
#include <hip/hip_runtime.h>

#define NDRUG 591
#define FDIM 1024
#define NEDGE 120000
#define MPAD 640
#define ASTRIDE 349281          // 591*591 (fp32 temp adjacency, unnormalized)
#define ABSTRIDE (MPAD*MPAD)    // 409600  (bf16 padded adjacency)
#define HSTRIDE (MPAD*FDIM)     // 655360  (bf16 padded node features)
#define REAL (NDRUG*FDIM)       // 605184  real (row-contiguous) elements
#define WSTRIDE (FDIM*FDIM)     // 1048576

typedef __attribute__((ext_vector_type(8))) short bf16x8;
typedef __attribute__((ext_vector_type(4))) float f32x4;
typedef __attribute__((ext_vector_type(4))) unsigned short u16x4;

static __device__ __forceinline__ unsigned short f2bf(float f) {
    unsigned u = __builtin_bit_cast(unsigned, f);
    u += 0x7fffu + ((u >> 16) & 1u);            // RNE
    return (unsigned short)(u >> 16);
}
static __device__ __forceinline__ float bf2f(unsigned short h) {
    return __builtin_bit_cast(float, ((unsigned)h) << 16);
}

typedef const __attribute__((address_space(1))) unsigned int* gp1_t;
typedef __attribute__((address_space(3))) unsigned int* lp3_t;
static __device__ __forceinline__ void gload16(const void* g, unsigned short* l) {
    __builtin_amdgcn_global_load_lds((gp1_t)g, (lp3_t)l, 16, 0, 0);
}

// ---------------- init: zero fp32 A (vectorized), zero pool acc ----------------
__global__ void init_kernel(float* AmatF, float* scal) {
    int i = blockIdx.x * blockDim.x + threadIdx.x;
    const int TOT = 3 * ASTRIDE;
    int b = i * 4;
    if (b + 3 < TOT) {
        *(float4*)(AmatF + b) = make_float4(0.f, 0.f, 0.f, 0.f);
    } else if (b < TOT) {
        for (int j = b; j < TOT; ++j) AmatF[j] = 0.f;
    }
    if (i < 16) scal[i] = 0.f;
}

// ---------------- raw edge-weight scatter + self-loop (+1 on diagonal) ----------------
__global__ void scatter_kernel(const int* e_t, const float* w_t,
                               const int* e_s, const float* w_s,
                               const int* e_g, const float* w_g, float* AmatF) {
    int i = blockIdx.x * blockDim.x + threadIdx.x;
    const int PER = NEDGE + NDRUG;
    if (i >= 3 * PER) return;
    int g = i / PER, r = i - g * PER;
    float* Ag = AmatF + (long)g * ASTRIDE;
    if (r < NEDGE) {
        const int*   E_ = (g == 0) ? e_t : (g == 1) ? e_s : e_g;
        const float* W_ = (g == 0) ? w_t : (g == 1) ? w_s : w_g;
        int src = E_[r], dst = E_[NEDGE + r];
        atomicAdd(Ag + (long)dst * NDRUG + src, W_[r]);
    } else {
        int n = r - NEDGE;
        atomicAdd(Ag + (long)n * NDRUG + n, 1.0f);      // self-loop weight 1
    }
}

// ---------------- deg = rowsum(A); dinv = rsqrt(deg) ----------------
__global__ void rowdeg_kernel(const float* AmatF, float* dinv) {
    int r = blockIdx.x, g = blockIdx.y;
    const float* row = AmatF + (long)g * ASTRIDE + (long)r * NDRUG;
    float s = 0.f;
    for (int c = threadIdx.x; c < NDRUG; c += 64) s += row[c];
#pragma unroll
    for (int off = 32; off > 0; off >>= 1) s += __shfl_down(s, off);
    if (threadIdx.x == 0)
        dinv[g * NDRUG + r] = (s > 0.f) ? rsqrtf(s) : 0.f;
}

// ---------------- fused normalize + bf16 convert + pad ----------------
__global__ void conv_A(const float* AmatF, const float* dinv, unsigned short* Amatb) {
    int r = blockIdx.x, g = blockIdx.y;
    int t = threadIdx.x;
    if (t >= 160) return;
    int c = t * 4;
    u16x4 o = {0, 0, 0, 0};
    if (r < NDRUG) {
        const float* src = AmatF + (long)g * ASTRIDE + (long)r * NDRUG;
        const float* dv = dinv + g * NDRUG;
        float dr = dv[r];
#pragma unroll
        for (int j = 0; j < 4; j++) {
            int cc = c + j;
            if (cc < NDRUG) o[j] = f2bf(src[cc] * dv[cc] * dr);
        }
    }
    *(u16x4*)(Amatb + (long)g * ABSTRIDE + (long)r * MPAD + c) = o;
}

// dm1 [591][1024] fp32 -> dm1b [640][1024] bf16, zero-padded
__global__ void conv_dm1(const float* dm1, unsigned short* dm1b) {
    int r = blockIdx.x;
    int c = threadIdx.x * 4;
    u16x4 o = {0, 0, 0, 0};
    if (r < NDRUG) {
        float4 v = *(const float4*)(dm1 + (long)r * FDIM + c);
        o[0] = f2bf(v.x); o[1] = f2bf(v.y); o[2] = f2bf(v.z); o[3] = f2bf(v.w);
    }
    *(u16x4*)(dm1b + (long)r * FDIM + c) = o;
}

// W [K][N] fp32 -> WT [N][K] bf16, all 6 matrices (order t1,s1,g1,t2,s2,g2)
__global__ void conv_w6(const float* w0, const float* w1, const float* w2,
                        const float* w3, const float* w4, const float* w5,
                        unsigned short* WTb) {
    __shared__ float s[32][33];
    int z = blockIdx.z;
    const float* W = (z == 0) ? w0 : (z == 1) ? w1 : (z == 2) ? w2
                   : (z == 3) ? w3 : (z == 4) ? w4 : w5;
    unsigned short* WT = WTb + (long)z * WSTRIDE;
    int n0 = blockIdx.x * 32, k0 = blockIdx.y * 32;
    int tx = threadIdx.x & 31, ty = threadIdx.x >> 5;   // ty 0..7
#pragma unroll
    for (int p = 0; p < 4; p++)
        s[ty + 8 * p][tx] = W[(long)(k0 + ty + 8 * p) * FDIM + n0 + tx];
    __syncthreads();
#pragma unroll
    for (int p = 0; p < 4; p++)
        WT[(long)(n0 + ty + 8 * p) * FDIM + k0 + tx] = f2bf(s[tx][ty + 8 * p]);
}

// ---------------- bf16 MFMA GEMM (counted-vmcnt pipelined 2-phase) ----------------
// C[m][n] = sum_k A[m][k] * BT[n][k]   (A: [Mpad][ldaK], BT: [N][ldbK], both bf16)
// EPI=0: store C transposed bf16 (C[n][m], ldC=MPAD); EPI=1: +bias, relu, normal
//        layout, and channel-sum of valid rows accumulated into poolacc[2g+layer].
template <int EPI>
__global__ __launch_bounds__(256) void mfma_gemm(
    const unsigned short* __restrict__ Abase, long strideA, int ldaK,
    const unsigned short* __restrict__ Bbase, long strideB, int ldbK,
    const float* __restrict__ bias0, const float* __restrict__ bias1,
    const float* __restrict__ bias2,
    unsigned short* __restrict__ Cbase, long strideC, int ldC, int K,
    float* __restrict__ poolacc, int layer)
{
    __shared__ unsigned short ldsA[2][4096];
    __shared__ unsigned short ldsB[2][4096];
    __shared__ float red[4];

    const int g = blockIdx.z;
    const unsigned short* A = Abase + (long)g * strideA;
    const unsigned short* B = Bbase + (long)g * strideB;
    unsigned short* C = Cbase + (long)g * strideC;
    const float* bias = (g == 0) ? bias0 : (g == 1) ? bias1 : bias2;

    const int m0 = blockIdx.y * 64;
    const int n0 = blockIdx.x * 64;
    const int tid = threadIdx.x;
    const int w = tid >> 6, lane = tid & 63;
    const int l15 = lane & 15, lq = lane >> 4;
    const int wm = w >> 1, wn = w & 1;

    // staging geometry: seg = 2w or 2w+1 covers tile rows [8*seg, 8*seg+8)
    const int sr  = lane >> 3;                  // row within segment
    const int kcs = 8 * ((lane & 7) ^ sr);      // pre-swizzled k element offset
    const int segA0 = 2 * w, segA1 = 2 * w + 1;
    const int rA0 = segA0 * 8 + sr, rA1 = segA1 * 8 + sr;

    // fragment ds_read offsets (elements), swizzled to match staging
    int offA[2][2], offB[2][2];
    {
        int ra0 = 32 * wm + l15, ra1 = ra0 + 16;
        int rb0 = 32 * wn + l15, rb1 = rb0 + 16;
        offA[0][0] = ra0 * 64 + ((lq    ) ^ (ra0 & 7)) * 8;
        offA[0][1] = ra0 * 64 + ((lq + 4) ^ (ra0 & 7)) * 8;
        offA[1][0] = ra1 * 64 + ((lq    ) ^ (ra1 & 7)) * 8;
        offA[1][1] = ra1 * 64 + ((lq + 4) ^ (ra1 & 7)) * 8;
        offB[0][0] = rb0 * 64 + ((lq    ) ^ (rb0 & 7)) * 8;
        offB[0][1] = rb0 * 64 + ((lq + 4) ^ (rb0 & 7)) * 8;
        offB[1][0] = rb1 * 64 + ((lq    ) ^ (rb1 & 7)) * 8;
        offB[1][1] = rb1 * 64 + ((lq + 4) ^ (rb1 & 7)) * 8;
    }

    f32x4 acc00 = {0.f, 0.f, 0.f, 0.f}, acc01 = {0.f, 0.f, 0.f, 0.f};
    f32x4 acc10 = {0.f, 0.f, 0.f, 0.f}, acc11 = {0.f, 0.f, 0.f, 0.f};

    const int nt = K >> 6;

#define STAGE(bf, k0c) do {                                                        \
    gload16(A + (long)(m0 + rA0) * ldaK + (k0c) + kcs, &ldsA[bf][segA0 * 512]);    \
    gload16(A + (long)(m0 + rA1) * ldaK + (k0c) + kcs, &ldsA[bf][segA1 * 512]);    \
    gload16(B + (long)(n0 + rA0) * ldbK + (k0c) + kcs, &ldsB[bf][segA0 * 512]);    \
    gload16(B + (long)(n0 + rA1) * ldbK + (k0c) + kcs, &ldsB[bf][segA1 * 512]);    \
} while (0)

    STAGE(0, 0);    // 4 loads in flight

    for (int t = 0; t < nt; ++t) {
        const int cur = t & 1;
        if (t + 1 < nt) {
            STAGE(cur ^ 1, (t + 1) << 6);               // 8 in flight
            asm volatile("s_waitcnt vmcnt(4)");         // tile t landed; t+1 stays in flight
        } else {
            asm volatile("s_waitcnt vmcnt(0)");         // last tile: drain
        }
        __builtin_amdgcn_s_barrier();                   // all waves: buf[cur] ready
        __builtin_amdgcn_sched_barrier(0);
        const unsigned short* pa = ldsA[cur];
        const unsigned short* pb = ldsB[cur];
        {
            bf16x8 a0 = *(const bf16x8*)(pa + offA[0][0]);
            bf16x8 a1 = *(const bf16x8*)(pa + offA[1][0]);
            bf16x8 b0 = *(const bf16x8*)(pb + offB[0][0]);
            bf16x8 b1 = *(const bf16x8*)(pb + offB[1][0]);
            acc00 = __builtin_amdgcn_mfma_f32_16x16x32_bf16(a0, b0, acc00, 0, 0, 0);
            acc01 = __builtin_amdgcn_mfma_f32_16x16x32_bf16(a0, b1, acc01, 0, 0, 0);
            acc10 = __builtin_amdgcn_mfma_f32_16x16x32_bf16(a1, b0, acc10, 0, 0, 0);
            acc11 = __builtin_amdgcn_mfma_f32_16x16x32_bf16(a1, b1, acc11, 0, 0, 0);
        }
        {
            bf16x8 a0 = *(const bf16x8*)(pa + offA[0][1]);
            bf16x8 a1 = *(const bf16x8*)(pa + offA[1][1]);
            bf16x8 b0 = *(const bf16x8*)(pb + offB[0][1]);
            bf16x8 b1 = *(const bf16x8*)(pb + offB[1][1]);
            acc00 = __builtin_amdgcn_mfma_f32_16x16x32_bf16(a0, b0, acc00, 0, 0, 0);
            acc01 = __builtin_amdgcn_mfma_f32_16x16x32_bf16(a0, b1, acc01, 0, 0, 0);
            acc10 = __builtin_amdgcn_mfma_f32_16x16x32_bf16(a1, b0, acc10, 0, 0, 0);
            acc11 = __builtin_amdgcn_mfma_f32_16x16x32_bf16(a1, b1, acc11, 0, 0, 0);
        }
        asm volatile("s_waitcnt lgkmcnt(0)");           // reads of buf[cur] complete
        __builtin_amdgcn_sched_barrier(0);
        __builtin_amdgcn_s_barrier();                   // release buf[cur] for overwrite
    }
#undef STAGE

    // epilogue: D layout col=lane&15, row=(lane>>4)*4+reg   [m89-verified]
    if (EPI == 0) {
#define TSTORE(accv, mo, no) do {                                   \
        int nn = n0 + 32 * wn + (no) * 16 + l15;                    \
        int mm = m0 + 32 * wm + (mo) * 16 + lq * 4;                 \
        u16x4 pk;                                                   \
        pk[0] = f2bf(accv[0]); pk[1] = f2bf(accv[1]);               \
        pk[2] = f2bf(accv[2]); pk[3] = f2bf(accv[3]);               \
        *(u16x4*)&C[(long)nn * ldC + mm] = pk;                      \
} while (0)
        TSTORE(acc00, 0, 0); TSTORE(acc01, 0, 1);
        TSTORE(acc10, 1, 0); TSTORE(acc11, 1, 1);
#undef TSTORE
    } else {
        float spool = 0.f;
#define NSTORE(accv, mo, no) do {                                   \
        int nn = n0 + 32 * wn + (no) * 16 + l15;                    \
        int mm = m0 + 32 * wm + (mo) * 16 + lq * 4;                 \
        float bs = bias[nn];                                        \
        _Pragma("unroll")                                           \
        for (int i = 0; i < 4; i++) {                               \
            float v = fmaxf(accv[i] + bs, 0.f);                     \
            C[(long)(mm + i) * ldC + nn] = f2bf(v);                 \
            if (mm + i < NDRUG) spool += v;                         \
        }                                                           \
} while (0)
        NSTORE(acc00, 0, 0); NSTORE(acc01, 0, 1);
        NSTORE(acc10, 1, 0); NSTORE(acc11, 1, 1);
#undef NSTORE
        // channel mean-pool contribution (sum of valid relu outputs)
#pragma unroll
        for (int off = 32; off > 0; off >>= 1) spool += __shfl_down(spool, off);
        if (lane == 0) red[w] = spool;
        __syncthreads();
        if (tid == 0)
            atomicAdd(poolacc + 2 * g + layer, red[0] + red[1] + red[2] + red[3]);
    }
}

// ---------------- SE MLP, 64-lane parallel ----------------
__global__ void mlp_kernel(const float* acc, const float* fc1w, const float* fc1b,
                           const float* fc2w, const float* fc2b, const float* convw,
                           float* wout) {
    __shared__ float hsh[30], plsh[6];
    int t = threadIdx.x;            // 64 threads
    const float inv = 1.0f / (float)REAL;
    if (t < 6) plsh[t] = acc[t] * inv;
    __syncthreads();
    if (t < 30) {
        float s = fc1b[t];
#pragma unroll
        for (int c = 0; c < 6; c++) s += plsh[c] * fc1w[t * 6 + c];
        hsh[t] = fmaxf(s, 0.f);
    }
    __syncthreads();
    float hv = (t < 30) ? hsh[t] : 0.f;
    for (int j = 0; j < 6; j++) {
        float p = (t < 30) ? hv * fc2w[j * 30 + t] : 0.f;
#pragma unroll
        for (int off = 32; off > 0; off >>= 1) p += __shfl_down(p, off);
        if (t == 0) {
            float s = fc2b[j] + p;
            wout[j] = convw[j] / (1.f + expf(-s));
        }
    }
}

__global__ void combine_kernel(const unsigned short* h1b, const unsigned short* h2b,
                               const float* wv, const float* convb, float* out) {
    int i = blockIdx.x * 256 + threadIdx.x;
    const int nv = REAL / 8;
    if (i >= nv) return;
    float cb = convb[0];
    float r[8];
#pragma unroll
    for (int j = 0; j < 8; j++) r[j] = cb;
#define ACCCH(c, ptr) do {                                          \
        float wc = wv[c];                                           \
        bf16x8 v = *(const bf16x8*)((ptr) + (long)i * 8);           \
        _Pragma("unroll")                                           \
        for (int j = 0; j < 8; j++) r[j] += wc * bf2f((unsigned short)v[j]); \
} while (0)
    ACCCH(0, h1b);
    ACCCH(1, h2b);
    ACCCH(2, h1b + HSTRIDE);
    ACCCH(3, h2b + HSTRIDE);
    ACCCH(4, h1b + 2 * HSTRIDE);
    ACCCH(5, h2b + 2 * HSTRIDE);
#undef ACCCH
    float4 o0 = make_float4(r[0], r[1], r[2], r[3]);
    float4 o1 = make_float4(r[4], r[5], r[6], r[7]);
    *(float4*)(out + (long)i * 8) = o0;
    *(float4*)(out + (long)i * 8 + 4) = o1;
}

extern "C" void kernel_launch(void* const* d_in, const int* in_sizes, int n_in,
                              void* d_out, int out_size, void* d_ws, size_t ws_size,
                              hipStream_t stream) {
    const float* dm1 = (const float*)d_in[0];
    const int*   e_t = (const int*)d_in[1];
    const float* w_t = (const float*)d_in[2];
    const int*   e_s = (const int*)d_in[3];
    const float* w_s = (const float*)d_in[4];
    const int*   e_g = (const int*)d_in[5];
    const float* w_g = (const float*)d_in[6];
    const float* W_t1 = (const float*)d_in[7];
    const float* b_t1 = (const float*)d_in[8];
    const float* W_t2 = (const float*)d_in[9];
    const float* b_t2 = (const float*)d_in[10];
    const float* W_s1 = (const float*)d_in[11];
    const float* b_s1 = (const float*)d_in[12];
    const float* W_s2 = (const float*)d_in[13];
    const float* b_s2 = (const float*)d_in[14];
    const float* W_g1 = (const float*)d_in[15];
    const float* b_g1 = (const float*)d_in[16];
    const float* W_g2 = (const float*)d_in[17];
    const float* b_g2 = (const float*)d_in[18];
    const float* fc1w = (const float*)d_in[19];
    const float* fc1b = (const float*)d_in[20];
    const float* fc2w = (const float*)d_in[21];
    const float* fc2b = (const float*)d_in[22];
    const float* convw = (const float*)d_in[23];
    const float* convb = (const float*)d_in[24];
    float* out = (float*)d_out;

    // workspace layout (bytes):
    //   WTb   : 6 weight mats bf16, 12,582,912 B
    //   AmatF : fp32 adjacency 4,191,372 B — ALIASES WTb[0..] (dead before conv_w6)
    //   h2b   : ALIASES WTb layer-2 half (dead after stage-2 GEMM)
    char* base = (char*)d_ws;
    unsigned short* WTb = (unsigned short*)base;
    float* AmatF = (float*)base;
    unsigned short* h2b = (unsigned short*)(base + (size_t)3 * WSTRIDE * 2);
    size_t o = (size_t)6 * WSTRIDE * 2;
    float* dinv = (float*)(base + o); o += 8192;
    float* scal = (float*)(base + o); o += 256;
    unsigned short* dm1b  = (unsigned short*)(base + o); o += (size_t)MPAD * FDIM * 2;
    unsigned short* Amatb = (unsigned short*)(base + o); o += (size_t)3 * ABSTRIDE * 2;
    unsigned short* xwT   = (unsigned short*)(base + o); o += (size_t)3 * HSTRIDE * 2;
    unsigned short* h1b   = (unsigned short*)(base + o); o += (size_t)3 * HSTRIDE * 2;
    if (ws_size < o) return;   // refuse to fault if workspace too small (24.2 MB)

    // dense adjacency: zero -> raw scatter (+1 diag) -> rowsum deg -> normalize+bf16
    init_kernel<<<(3 * ASTRIDE / 4 + 256) / 256, 256, 0, stream>>>(AmatF, scal);
    scatter_kernel<<<(3 * (NEDGE + NDRUG) + 255) / 256, 256, 0, stream>>>(
        e_t, w_t, e_s, w_s, e_g, w_g, AmatF);
    rowdeg_kernel<<<dim3(NDRUG, 3), 64, 0, stream>>>(AmatF, dinv);
    conv_A<<<dim3(MPAD, 3), 256, 0, stream>>>(AmatF, dinv, Amatb);
    conv_w6<<<dim3(32, 32, 6), 256, 0, stream>>>(
        W_t1, W_s1, W_g1, W_t2, W_s2, W_g2, WTb);    // overwrites AmatF alias (dead)
    conv_dm1<<<MPAD, 256, 0, stream>>>(dm1, dm1b);

    dim3 gg(FDIM / 64, MPAD / 64, 3);
    // stage 1: xwT = (dm1b @ W1)^T
    mfma_gemm<0><<<gg, 256, 0, stream>>>(
        dm1b, 0L, FDIM, WTb, (long)WSTRIDE, FDIM,
        nullptr, nullptr, nullptr, xwT, (long)HSTRIDE, MPAD, FDIM, scal, 0);
    // agg 1: h1 = relu(A @ xw + b1)  (+pool into scal[2g])
    mfma_gemm<1><<<gg, 256, 0, stream>>>(
        Amatb, (long)ABSTRIDE, MPAD, xwT, (long)HSTRIDE, MPAD,
        b_t1, b_s1, b_g1, h1b, (long)HSTRIDE, FDIM, MPAD, scal, 0);
    // stage 2: xwT = (h1 @ W2)^T   (consumes WTb layer-2 half)
    mfma_gemm<0><<<gg, 256, 0, stream>>>(
        h1b, (long)HSTRIDE, FDIM, WTb + (size_t)3 * WSTRIDE, (long)WSTRIDE, FDIM,
        nullptr, nullptr, nullptr, xwT, (long)HSTRIDE, MPAD, FDIM, scal, 0);
    // agg 2: h2 = relu(A @ xw + b2)  (+pool into scal[2g+1]; h2b aliases dead WTb half)
    mfma_gemm<1><<<gg, 256, 0, stream>>>(
        Amatb, (long)ABSTRIDE, MPAD, xwT, (long)HSTRIDE, MPAD,
        b_t2, b_s2, b_g2, h2b, (long)HSTRIDE, FDIM, MPAD, scal, 1);

    mlp_kernel<<<1, 64, 0, stream>>>(scal, fc1w, fc1b, fc2w, fc2b, convw, scal + 8);
    combine_kernel<<<(REAL / 8 + 255) / 256, 256, 0, stream>>>(h1b, h2b, scal + 8, convb, out);
}